// Round 1
// baseline (74.968 us; speedup 1.0000x reference)
//
#include <hip/hip_runtime.h>
#include <math.h>

// Problem constants (from reference setup_inputs)
#define B   64
#define NJ  42
#define NP  16384
#define CHUNKS 16
#define PC  (NP / CHUNKS)   // 1024 points per block
#define TPB 256
#define PPT (PC / TPB)      // 4 points per thread
#define NPAIR (PPT / 2)     // 2 float2 pairs per thread
#define HJ  (NJ / 2)        // 21 joints per reduction half (halves LDS)
#define RSTRIDE 260         // row stride (floats): mult of 4 (aligned b128), >TPB
#define NQ  (B * NJ / 4)    // 672 float4 groups of (b,j) pairs

typedef float v2f __attribute__((ext_vector_type(2)));

// Per-(b,chunk) block: min over its 1024 points of (0.5*|p|^2 - a.p) for all
// 42 joints, finalized to clamped d^2 and stored as a partial (no atomics,
// no device-scope fences — R3 showed agent-scope release = buffer_wbl2 per
// block, an ~18 us regression).
__global__ __launch_bounds__(TPB) void sdl_min_kernel(
    const float* __restrict__ joints,   // [B, NJ, 3]
    const float* __restrict__ pts,      // [B, NP, 3]
    float* __restrict__ part)           // [CHUNKS][B*NJ] partial clamped d^2
{
    __shared__ __align__(16) float4 sj[NJ];               // joint xyz + |a|^2
    __shared__ __align__(16) float  red[HJ * RSTRIDE];    // 21.8 KB transpose scratch

    const int tid = threadIdx.x;
    const int b   = blockIdx.x >> 4;            // / CHUNKS
    const int ch  = blockIdx.x & (CHUNKS - 1);  // % CHUNKS

    // Stage joints: xyz and |a|^2
    if (tid < NJ) {
        const float* jp = joints + (b * NJ + tid) * 3;
        float x = jp[0], y = jp[1], z = jp[2];
        sj[tid] = make_float4(x, y, z, fmaf(x, x, fmaf(y, y, z * z)));
    }

    // 4 consecutive points per thread via 3 global_load_dwordx4 (48 B,
    // 16B-aligned: (b*16384 + ch*1024)*12 B is a multiple of 16).
    const float4* pb4 = (const float4*)(pts + (size_t)(b * NP + ch * PC) * 3);
    float4 P0 = pb4[3 * tid + 0];
    float4 P1 = pb4[3 * tid + 1];
    float4 P2 = pb4[3 * tid + 2];

    // NEGATED coords and q = 0.5*|p|^2 so the inner loop is a pure 3-FMA chain.
    v2f npx[NPAIR], npy[NPAIR], npz[NPAIR], q[NPAIR];
    {
        float x0 = P0.x, y0 = P0.y, z0 = P0.z;
        float x1 = P0.w, y1 = P1.x, z1 = P1.y;
        float x2 = P1.z, y2 = P1.w, z2 = P2.x;
        float x3 = P2.y, y3 = P2.z, z3 = P2.w;
        npx[0] = (v2f){-x0, -x1}; npy[0] = (v2f){-y0, -y1}; npz[0] = (v2f){-z0, -z1};
        q[0]   = (v2f){0.5f * fmaf(x0, x0, fmaf(y0, y0, z0 * z0)),
                       0.5f * fmaf(x1, x1, fmaf(y1, y1, z1 * z1))};
        npx[1] = (v2f){-x2, -x3}; npy[1] = (v2f){-y2, -y3}; npz[1] = (v2f){-z2, -z3};
        q[1]   = (v2f){0.5f * fmaf(x2, x2, fmaf(y2, y2, z2 * z2)),
                       0.5f * fmaf(x3, x3, fmaf(y3, y3, z3 * z3))};
    }
    __syncthreads();

    // Per-thread running min of (q - a.p) per joint.
    float m[NJ];
#pragma unroll
    for (int j = 0; j < NJ; ++j) m[j] = 3.0e38f;

#pragma unroll
    for (int j = 0; j < NJ; ++j) {
        float4 Jv = sj[j];                 // broadcast ds_read_b128
        v2f jx = (v2f){Jv.x, Jv.x};
        v2f jy = (v2f){Jv.y, Jv.y};
        v2f jz = (v2f){Jv.z, Jv.z};
        float mj = m[j];
#pragma unroll
        for (int k = 0; k < NPAIR; ++k) {
            v2f t = npz[k] * jz + q[k];    // v_pk_fma_f32
            t     = npy[k] * jy + t;
            t     = npx[k] * jx + t;
            mj = fminf(fminf(mj, t.x), t.y);   // -> v_min3_f32
        }
        m[j] = mj;
    }

    // Block reduction via LDS transpose, two halves of 21 joints (keeps LDS
    // at 22.5 KB -> not the occupancy limiter). 4 threads per joint row:
    // each reduces 16 float4, then a 2-step shfl_xor combine (chain 63 -> ~17).
#pragma unroll
    for (int h = 0; h < 2; ++h) {
        if (h) __syncthreads();            // h=1 writes wait for h=0 reads
#pragma unroll
        for (int jj = 0; jj < HJ; ++jj) red[jj * RSTRIDE + tid] = m[h * HJ + jj];
        __syncthreads();
        if (tid < 4 * HJ) {                // 84 threads: 4 per joint
            const int jj = tid >> 2;
            const int qt = tid & 3;
            const float4* row = (const float4*)(red + jj * RSTRIDE) + qt * (TPB / 16);
            float4 a = row[0];
#pragma unroll
            for (int i = 1; i < TPB / 16; ++i) {
                float4 v = row[i];
                a.x = fminf(a.x, v.x); a.y = fminf(a.y, v.y);
                a.z = fminf(a.z, v.z); a.w = fminf(a.w, v.w);
            }
            float mn = fminf(fminf(a.x, a.y), fminf(a.z, a.w));
            mn = fminf(mn, __shfl_xor(mn, 1));  // groups of 4 never cross a wave
            mn = fminf(mn, __shfl_xor(mn, 2));
            if (qt == 0) {
                const int j = h * HJ + jj;
                // d^2 = 2*min(q - a.p) + |a|^2, clamped (commutes with min)
                float d2 = fmaxf(fmaf(2.0f, mn, sj[j].w), 0.0f);
                part[ch * (B * NJ) + b * NJ + j] = d2;
            }
        }
    }
}

__global__ __launch_bounds__(1024) void sdl_final_kernel(
    const float4* __restrict__ part4,   // [CHUNKS][NQ] float4 view of partials
    const float4* __restrict__ gt4,     // [NQ] float4 view of gt
    float* __restrict__ out)            // [1]
{
    const int tid = threadIdx.x;
    float acc = 0.0f;
    if (tid < NQ) {                      // 672 < 1024: single pass, float4 loads
        float4 mn = part4[tid];
#pragma unroll
        for (int c = 1; c < CHUNKS; ++c) {
            float4 v = part4[c * NQ + tid];
            mn.x = fminf(mn.x, v.x); mn.y = fminf(mn.y, v.y);
            mn.z = fminf(mn.z, v.z); mn.w = fminf(mn.w, v.w);
        }
        float4 g = gt4[tid];
        float dx = sqrtf(mn.x) - g.x;
        float dy = sqrtf(mn.y) - g.y;
        float dz = sqrtf(mn.z) - g.z;
        float dw = sqrtf(mn.w) - g.w;
        acc = fmaf(dx, dx, fmaf(dy, dy, fmaf(dz, dz, dw * dw)));
    }
#pragma unroll
    for (int off = 32; off > 0; off >>= 1)
        acc += __shfl_xor(acc, off);
    __shared__ float wsum[16];
    if ((tid & 63) == 0) wsum[tid >> 6] = acc;
    __syncthreads();
    if (tid == 0) {
        float s = 0.0f;
#pragma unroll
        for (int w = 0; w < 16; ++w) s += wsum[w];
        out[0] = s * (1.0f / (B * NJ));
    }
}

extern "C" void kernel_launch(void* const* d_in, const int* in_sizes, int n_in,
                              void* d_out, int out_size, void* d_ws, size_t ws_size,
                              hipStream_t stream) {
    const float* pred = (const float*)d_in[0];   // [B,NJ,3]
    const float* obj  = (const float*)d_in[1];   // [B,NP,3]
    const float* gt   = (const float*)d_in[2];   // [B,NJ]
    float* part = (float*)d_ws;                  // CHUNKS*B*NJ floats (172 KB)

    sdl_min_kernel<<<B * CHUNKS, TPB, 0, stream>>>(pred, obj, part);
    sdl_final_kernel<<<1, 1024, 0, stream>>>((const float4*)part,
                                             (const float4*)gt, (float*)d_out);
}